// Round 3
// baseline (236.484 us; speedup 1.0000x reference)
//
#include <hip/hip_runtime.h>
#include <hip/hip_bf16.h>

// KAN layer = GEMM: out[b,o] = sum_{i,k} T_k(tanh(x[b,i])) * W[o,i,k] + bias[o]
// FUSED v2: A is never materialized AND never touches LDS.
//   For mfma_16x16x32 the A-fragment of a lane is k = qk*8+j (j=0..7), which is
//   exactly T_0..T_7 of ONE feature f = kt/8 + s*4 + qk. Each lane computes its
//   own A-fragment with one cheb8() straight into registers.
// Pipeline: triple-buffered B in LDS, ONE raw s_barrier per K-step, counted
//   s_waitcnt vmcnt(8) (4 B-stage + 4 x-prefetch loads stay in flight across
//   the barrier). Skew safety: iter t stages buf[(t+1)%3]; a wave can be at
//   most one barrier ahead, so writes never collide with readers of buf[t%3].
#define MD 4096
#define ND 1024
#define KD 8192
#define IN_F 1024

typedef __bf16 bf16x8 __attribute__((ext_vector_type(8)));
typedef float f32x4 __attribute__((ext_vector_type(4)));

// ---------------- Pass 1: W fp32 -> bf16 (48 MB traffic, ~10 us) ----------
#define N_CONV ((ND * KD) / 8)

__global__ __launch_bounds__(256) void conv_kernel(
    const float* __restrict__ w, __bf16* __restrict__ B) {
  int j = blockIdx.x * blockDim.x + threadIdx.x;  // grid is exact, no tail
  const float4* p = (const float4*)(w + (size_t)j * 8);
  float4 a = p[0], b = p[1];
  bf16x8 v;
  v[0] = (__bf16)a.x; v[1] = (__bf16)a.y; v[2] = (__bf16)a.z; v[3] = (__bf16)a.w;
  v[4] = (__bf16)b.x; v[5] = (__bf16)b.y; v[6] = (__bf16)b.z; v[7] = (__bf16)b.w;
  *(bf16x8*)(B + (size_t)j * 8) = v;
}

// ---------------- Pass 2: fused basis + GEMM_BT + bias ----------------
#define BM 64
#define BN 128
#define BK 64
#define NT (KD / BK)      // 128 K-steps
#define BUFSZ (BN * BK)   // 8192 bf16 = 16 KB per buffer

__device__ __forceinline__ bf16x8 cheb8(float xs) {
  // fast tanh: copysign(1 - 2/(exp2(2*log2(e)*|x|) + 1), x)
  // |err| ~1e-7, far below bf16 rounding; verified absmax-neutral in R1.
  float ax = __builtin_fabsf(xs);
  float e = __builtin_amdgcn_exp2f(ax * 2.88539008177792681472f);
  float r = __builtin_amdgcn_rcpf(e + 1.0f);
  float t = 1.0f - 2.0f * r;
  t = __builtin_copysignf(t, xs);
  float two_t = 2.0f * t;
  float T0 = 1.0f;
  float T1 = t;
  float T2 = two_t * T1 - T0;
  float T3 = two_t * T2 - T1;
  float T4 = two_t * T3 - T2;
  float T5 = two_t * T4 - T3;
  float T6 = two_t * T5 - T4;
  float T7 = two_t * T6 - T5;
  bf16x8 v;
  v[0] = (__bf16)T0; v[1] = (__bf16)T1; v[2] = (__bf16)T2; v[3] = (__bf16)T3;
  v[4] = (__bf16)T4; v[5] = (__bf16)T5; v[6] = (__bf16)T6; v[7] = (__bf16)T7;
  return v;
}

__global__ __launch_bounds__(256) void gemm_bias(
    const float* __restrict__ x, const __bf16* __restrict__ B,
    const float* __restrict__ bias, float* __restrict__ C) {
  __shared__ __align__(16) __bf16 Bs[3 * BUFSZ];  // 48 KB

  const int tid = threadIdx.x;
  const int wave = tid >> 6;
  const int lane = tid & 63;
  const int n0 = blockIdx.x * BN;   // gridDim.x == 8 == NXCD: each XCD keeps
  const int m0 = blockIdx.y * BM;   // its own 2 MB B-panel L2-resident.
  const int wm = wave >> 1;   // 0..1
  const int wn = wave & 1;    // 0..1

  // ---- B staging: one global_load_lds (16B/lane) covers 8 rows of 128B.
  // XOR swizzle applied on the GLOBAL address side (LDS dst must be linear).
  const int ar = lane >> 3;                  // 0..7
  const int swz_col = ((lane & 7) ^ ar) * 8;
  const __bf16* gB = B + (size_t)(n0 + wave * 32 + ar) * KD + swz_col;
  const int lBoff = (wave * 32) * BK;

  // ---- fragment coords (16x16x32: row=lane&15, k=(lane>>4)*8+j)
  const int fr = lane & 15;
  const int fr7 = fr & 7;
  const int qk = lane >> 4;  // 0..3

  // ---- x pointers: lane owns rows (wm*32+fr) and (+16); feature f = 8t+s*4+qk
  const float* xr0 = x + (size_t)(m0 + wm * 32 + fr) * IN_F + qk;
  const float* xr1 = xr0 + 16 * IN_F;

  f32x4 acc[2][4];
#pragma unroll
  for (int i = 0; i < 2; i++)
#pragma unroll
    for (int j = 0; j < 4; j++) acc[i][j] = (f32x4){0.f, 0.f, 0.f, 0.f};

  // ---- prologue: stage t=0 into buf0; load x for t=0
#pragma unroll
  for (int j = 0; j < 4; j++)
    __builtin_amdgcn_global_load_lds(
        (const __attribute__((address_space(1))) void*)(gB + (size_t)j * 8 * KD),
        (__attribute__((address_space(3))) void*)(Bs + lBoff + j * 8 * BK), 16, 0, 0);
  float xc0 = xr0[0], xc1 = xr0[4], xc2 = xr1[0], xc3 = xr1[4];

  int cur = 0, nxt = 1;
  for (int t = 0; t < NT; ++t) {
    const int tn = (t + 1 < NT) ? t + 1 : 0;  // wrap: keeps vmcnt count uniform
    const __bf16* lB = Bs + cur * BUFSZ;
    __bf16* sB = Bs + nxt * BUFSZ;

    // stage t+1 (4 loads) — stays in flight across the barrier
#pragma unroll
    for (int j = 0; j < 4; j++)
      __builtin_amdgcn_global_load_lds(
          (const __attribute__((address_space(1))) void*)(gB + (size_t)tn * BK + (size_t)j * 8 * KD),
          (__attribute__((address_space(3))) void*)(sB + lBoff + j * 8 * BK), 16, 0, 0);
    // x prefetch for t+1 (4 loads)
    float xn0 = xr0[tn * 8];
    float xn1 = xr0[tn * 8 + 4];
    float xn2 = xr1[tn * 8];
    float xn3 = xr1[tn * 8 + 4];

    // counted wait: the 8 newest (this iter's stage+x) may stay outstanding;
    // everything older (iter t's B-stage and x) is complete.
    asm volatile("s_waitcnt vmcnt(8)" ::: "memory");
    __builtin_amdgcn_s_barrier();
    __builtin_amdgcn_sched_barrier(0);

    // A-fragments straight from registers (no LDS):
    // a_rc = T_0..T_7(tanh(x[row_r, f])), f = 8t + s*4 + qk
    bf16x8 a00 = cheb8(xc0);  // row0, s=0
    bf16x8 a01 = cheb8(xc1);  // row0, s=1
    bf16x8 a10 = cheb8(xc2);  // row1, s=0
    bf16x8 a11 = cheb8(xc3);  // row1, s=1

#pragma unroll
    for (int s = 0; s < 2; s++) {
      const int pa = ((s * 4 + qk) ^ fr7) * 8;  // logical group ^ (row&7)
      bf16x8 bfr[4];
#pragma unroll
      for (int ni = 0; ni < 4; ni++)
        bfr[ni] = *(const bf16x8*)&lB[(wn * 64 + ni * 16 + fr) * BK + pa];
      bf16x8 af0 = s ? a01 : a00;
      bf16x8 af1 = s ? a11 : a10;
#pragma unroll
      for (int ni = 0; ni < 4; ni++) {
        acc[0][ni] = __builtin_amdgcn_mfma_f32_16x16x32_bf16(af0, bfr[ni], acc[0][ni], 0, 0, 0);
        acc[1][ni] = __builtin_amdgcn_mfma_f32_16x16x32_bf16(af1, bfr[ni], acc[1][ni], 0, 0, 0);
      }
    }

    xc0 = xn0; xc1 = xn1; xc2 = xn2; xc3 = xn3;
    cur = nxt;
    nxt = (nxt == 2) ? 0 : nxt + 1;
  }

  // ---- epilogue: C/D layout col=lane&15, row=(lane>>4)*4+r ; add bias
  const int col0 = n0 + wn * 64;
  const int row0 = m0 + wm * 32 + (lane >> 4) * 4;
#pragma unroll
  for (int ni = 0; ni < 4; ni++) {
    int col = col0 + ni * 16 + (lane & 15);
    float bv = bias[col];
#pragma unroll
    for (int mi = 0; mi < 2; mi++) {
      int row = row0 + mi * 16;
#pragma unroll
      for (int r = 0; r < 4; r++)
        C[(size_t)(row + r) * ND + col] = acc[mi][ni][r] + bv;
    }
  }
}

extern "C" void kernel_launch(void* const* d_in, const int* in_sizes, int n_in,
                              void* d_out, int out_size, void* d_ws, size_t ws_size,
                              hipStream_t stream) {
  const float* x = (const float*)d_in[0];     // [4096,1024]
  const float* w = (const float*)d_in[1];     // [1024,1024,8]
  const float* bias = (const float*)d_in[2];  // [1024]
  float* out = (float*)d_out;                 // [4096,1024]

  __bf16* Bbf = (__bf16*)d_ws;  // 1024*8192 bf16 = 16 MB

  conv_kernel<<<N_CONV / 256, 256, 0, stream>>>(w, Bbf);

  dim3 grid(ND / BN, MD / BM);  // (8, 64) = 512 blocks -> 2 blocks/CU
  gemm_bias<<<grid, 256, 0, stream>>>(x, Bbf, bias, out);
}